// Round 5
// baseline (165.671 us; speedup 1.0000x reference)
//
#include <hip/hip_runtime.h>
#include <stdint.h>

#define EPS 1e-8f

constexpr int HW = 16384;   // pixels per image (M and N dims)
constexpr int BM = 128;     // block M tile
constexpr int NG = 2048;    // n-group width per block (32 q-substeps of 64)

typedef __attribute__((ext_vector_type(4))) float floatx4;
typedef __attribute__((ext_vector_type(4))) int   intx4;
typedef __attribute__((ext_vector_type(8))) int   intx8;    // 32B = one f8f6f4 K=128 operand
typedef unsigned char u8;
typedef unsigned int u32;
typedef unsigned long long u64;

// Address-space-qualified pointers for global_load_lds (hipcc does NOT
// implicitly convert generic pointers to AS(1)/AS(3) builtin params).
typedef const __attribute__((address_space(1))) u32 gas_u32;
typedef __attribute__((address_space(3))) u32 las_u32;
__device__ inline void stage16(const void* g, void* l) {
    __builtin_amdgcn_global_load_lds((gas_u32*)g, (las_u32*)l, 16, 0, 0);
}

// HW packed fp8 e4m3 convert: 4 floats -> 4 bytes (2x v_cvt_pk_fp8_f32)
__device__ inline u32 pk4(float x0, float x1, float x2, float x3) {
    int t = __builtin_amdgcn_cvt_pk_fp8_f32(x0, x1, 0, false);
    t = __builtin_amdgcn_cvt_pk_fp8_f32(x2, x3, t, true);
    return (u32)t;
}

__device__ inline float getc(const float4& f, int j) {
    return (j == 0) ? f.x : (j == 1) ? f.y : (j == 2) ? f.z : f.w;
}

// ---------------------------------------------------------------------------
// Fragment layout (split-half, ds_read-conflict-free): pixel p, channel c:
//   g = p>>4 (16-px slab), r = p&15, kb = c>>7, q = (c>>5)&3, h = (c>>4)&1,
//   e8 = c&15;  byte = g*4096 + kb*2048 + h*1024 + (q*16+r)*16 + e8
// Lane (q*16+r) of an MFMA operand assembles its 32 contiguous k-bytes from
// two 16B halves at +0/+1024 (lane-stride-16 b128 = conflict-free banking,
// R4 measured SQ_LDS_BANK_CONFLICT = 0).
// A 64-col slice (4 slabs) is 16KB CONTIGUOUS -> linear global_load_lds.
//
// PREP (unchanged from R4, known-passing): 512 blocks x 512 threads.
// Thread (pg=tid&7, tc=tid>>3) covers pixels pg*4..+3 x channels tc*4..+3.
// Also zeroes packed/out (absorbs the memset launches).
__global__ __launch_bounds__(512) void prep_kernel(const float* __restrict__ a,
                                                   const float* __restrict__ b,
                                                   float* __restrict__ sumsq_a,
                                                   float* __restrict__ sumsq_b,
                                                   u8* __restrict__ aF, u8* __restrict__ bF,
                                                   u64* __restrict__ packed,
                                                   float* __restrict__ out) {
    __shared__ float red[64][33];
    __shared__ float invb_sh[32];
    const int tid = threadIdx.x;
    const int pg = tid & 7, tc = tid >> 3;
    const int p0 = blockIdx.x * 32, pb = pg * 4;
    const int c0 = tc * 4;
    const u32 fb = (u32)((c0 >> 7) * 2048 + ((c0 >> 4) & 1) * 1024 + (c0 & 15));
    const u32 qr16 = (u32)(((c0 >> 5) & 3) * 16);   // q*16 (row offset added per pixel)

    if (blockIdx.x < 32) packed[(size_t)blockIdx.x * 512 + tid] = 0ull;
    if (blockIdx.x == 0 && tid == 0) *out = 0.f;

    // hoisted loads (8 independent float4 in flight)
    float4 bv[4], av[4];
    #pragma unroll
    for (int i = 0; i < 4; ++i)
        bv[i] = *(const float4*)&b[(size_t)(c0 + i) * HW + p0 + pb];
    #pragma unroll
    for (int i = 0; i < 4; ++i)
        av[i] = *(const float4*)&a[(size_t)(c0 + i) * HW + p0 + pb];

    float s0 = 0.f, s1 = 0.f, s2 = 0.f, s3 = 0.f;
    #pragma unroll
    for (int i = 0; i < 4; ++i) {
        s0 += bv[i].x * bv[i].x; s1 += bv[i].y * bv[i].y;
        s2 += bv[i].z * bv[i].z; s3 += bv[i].w * bv[i].w;
    }
    red[tc][pb] = s0; red[tc][pb + 1] = s1; red[tc][pb + 2] = s2; red[tc][pb + 3] = s3;
    __syncthreads();
    if (tid < 32) {
        float B = 0.f;
        #pragma unroll
        for (int j = 0; j < 64; ++j) B += red[j][tid];
        sumsq_b[p0 + tid] = B;
        invb_sh[tid] = 1.0f / (sqrtf(B + EPS) + EPS);
    }
    __syncthreads();

    // b fragment stores (normalized), one u32 per pixel
    #pragma unroll
    for (int j = 0; j < 4; ++j) {
        const int p = p0 + pb + j;
        const float inv = invb_sh[pb + j];
        u32 wv = pk4(getc(bv[0], j) * inv, getc(bv[1], j) * inv,
                     getc(bv[2], j) * inv, getc(bv[3], j) * inv);
        *(u32*)(bF + ((size_t)(p >> 4) << 12) + fb + (qr16 + (u32)(p & 15)) * 16) = wv;
    }

    // a: sumsq partials + raw fragment stores
    s0 = s1 = s2 = s3 = 0.f;
    #pragma unroll
    for (int i = 0; i < 4; ++i) {
        s0 += av[i].x * av[i].x; s1 += av[i].y * av[i].y;
        s2 += av[i].z * av[i].z; s3 += av[i].w * av[i].w;
    }
    red[tc][pb] = s0; red[tc][pb + 1] = s1; red[tc][pb + 2] = s2; red[tc][pb + 3] = s3;
    #pragma unroll
    for (int j = 0; j < 4; ++j) {
        const int p = p0 + pb + j;
        u32 wv = pk4(getc(av[0], j), getc(av[1], j), getc(av[2], j), getc(av[3], j));
        *(u32*)(aF + ((size_t)(p >> 4) << 12) + fb + (qr16 + (u32)(p & 15)) * 16) = wv;
    }
    __syncthreads();
    if (tid < 32) {
        float A = 0.f;
        #pragma unroll
        for (int j = 0; j < 64; ++j) A += red[j][tid];
        sumsq_a[p0 + tid] = A;
    }
}

// ---------------------------------------------------------------------------
// G: fused GEMM + argmax, MX-scaled fp8 (unit scales).
// R4 post-mortem: MfmaUtil 39% with the mfma pipe floor met exactly ->
// the pipe starves during the per-qt {acc drain -> argmax VALU -> barrier}
// serial segment at 3 waves/SIMD. This version:
//   (1) 8 waves/block (512 thr), wave tile 32x32: per-wave state halves
//       (Afr 32 + accA/accB 16+16 + best 16 ~ 112 regs) -> 4 waves/SIMD.
//   (2) acc double-buffer (accA/accB, static names): argmax of qt-1 issues
//       while qt's mfmas occupy the pipe - VALU tail fully overlapped.
// Same 64 mfma/block/qt, same 16KB/qt LDS slices, same conflict-free
// stride-16 ds_read_b128 pattern (R4: 0 conflicts).
#define MFMA1(A_, B_, C_) __builtin_amdgcn_mfma_scale_f32_16x16x128_f8f6f4( \
        (A_), (B_), (C_), 0, 0, 0, SCL, 0, SCL)

#define LDB(off_) __builtin_shufflevector(                                  \
        *(const intx4*)(Lb + (off_)), *(const intx4*)(Lb + (off_) + 1024),  \
        0, 1, 2, 3, 4, 5, 6, 7)

#define MFMA_QT(acc_, buf_) do {                                            \
    const u8* Lb = &sB[buf_][(u32)(wn * 2) * 4096u + (u32)lane * 16u];      \
    intx8 Bk0n0 = LDB(0);                                                   \
    intx8 Bk0n1 = LDB(4096);                                                \
    __builtin_amdgcn_s_setprio(1);                                          \
    acc_[0][0] = MFMA1(Afr[0][0], Bk0n0, C64);                              \
    acc_[1][0] = MFMA1(Afr[1][0], Bk0n0, C64);                              \
    acc_[0][1] = MFMA1(Afr[0][0], Bk0n1, C64);                              \
    acc_[1][1] = MFMA1(Afr[1][0], Bk0n1, C64);                              \
    __builtin_amdgcn_s_setprio(0);                                          \
    intx8 Bk1n0 = LDB(2048);                                                \
    intx8 Bk1n1 = LDB(4096 + 2048);                                         \
    __builtin_amdgcn_s_setprio(1);                                          \
    acc_[0][0] = MFMA1(Afr[0][1], Bk1n0, acc_[0][0]);                       \
    acc_[1][0] = MFMA1(Afr[1][1], Bk1n0, acc_[1][0]);                       \
    acc_[0][1] = MFMA1(Afr[0][1], Bk1n1, acc_[0][1]);                       \
    acc_[1][1] = MFMA1(Afr[1][1], Bk1n1, acc_[1][1]);                       \
    __builtin_amdgcn_s_setprio(0);                                          \
} while (0)

#define ARGMAX_QT(acc_, qt_) do {                                           \
    const u32 qb_ = q0 + (u32)(qt_) * 64u;                                  \
    _Pragma("unroll")                                                       \
    for (int mi = 0; mi < 2; ++mi) {                                        \
        _Pragma("unroll")                                                   \
        for (int ni = 0; ni < 2; ++ni) {                                    \
            const u32 qc_ = qb_ + (u32)(ni * 16);                           \
            _Pragma("unroll")                                               \
            for (int r = 0; r < 4; ++r) {                                   \
                float v_ = acc_[mi][ni][r];                                 \
                bool gt_ = v_ > bestv[mi][r];                               \
                bestv[mi][r] = gt_ ? v_ : bestv[mi][r];                     \
                bestq[mi][r] = gt_ ? qc_ : bestq[mi][r];                    \
            }                                                               \
        }                                                                   \
    }                                                                       \
} while (0)

#define STAGE(buf_, qt_) do {                                               \
    const u8* gs_ = gQ + (u32)(qt_) * 16384u + so;                          \
    stage16(gs_, &sB[buf_][wso]);                                           \
    stage16(gs_ + 1024, &sB[buf_][wso + 1024]);                             \
} while (0)

__global__ __launch_bounds__(512, 4) void gemm_argmax(const u8* __restrict__ aF,
                                                      const u8* __restrict__ bF,
                                                      u64* __restrict__ packed) {
    __shared__ u8 sB[2][16384];
    const int tid = threadIdx.x;
    const int w = tid >> 6, lane = tid & 63;
    const int q4 = lane >> 4, r15 = lane & 15;
    const int wm = w >> 1, wn = w & 1;     // 4m x 2n waves, wave tile 32x32

    const u32 bid = blockIdx.x;
    const u32 ng = bid & 7;          // n-group -> XCD (L2-resident B panel)
    const u32 mt = bid >> 3;         // 0..127 M tile
    const int p0 = (int)mt * BM;

    // A fragments resident: slab g = mt*8 + wm*2 + mi; two 16B halves at
    // g*4096 + kb*2048 + {0,1024} + lane*16
    const u8* gA = aF + (((size_t)(mt * 8 + wm * 2)) << 12) + (u32)lane * 16;
    intx8 Afr[2][2];
    #pragma unroll
    for (int mi = 0; mi < 2; ++mi)
        #pragma unroll
        for (int kb = 0; kb < 2; ++kb)
            Afr[mi][kb] = __builtin_shufflevector(
                *(const intx4*)(gA + (u32)(mi * 4096 + kb * 2048)),
                *(const intx4*)(gA + (u32)(mi * 4096 + kb * 2048 + 1024)),
                0, 1, 2, 3, 4, 5, 6, 7);

    // B panel for this ng: qt slice = gQ + qt*16384, 16KB contiguous
    const u8* gQ = bF + ((size_t)ng << 19);
    const u32 so  = (u32)w * 2048u + (u32)lane * 16u;   // stage src offset (per-lane)
    const u32 wso = (u32)w * 2048u;                      // stage LDS dest (wave-uniform)

    float bestv[2][4];
    u32   bestq[2][4];
    #pragma unroll
    for (int mi = 0; mi < 2; ++mi)
        #pragma unroll
        for (int r = 0; r < 4; ++r) { bestv[mi][r] = -3.4e38f; bestq[mi][r] = 0; }

    const u32 q0 = ng * 2048 + wn * 32 + (u32)r15;   // + qt*64 + ni*16
    const floatx4 C64 = {64.f, 64.f, 64.f, 64.f};
    const int SCL = 0x7F7F7F7F;      // E8M0 127 = 2^0 -> unit scale

    floatx4 accA[2][2], accB[2][2];

    STAGE(0, 0);
    __syncthreads();                 // buf0 (qt0) ready

    STAGE(1, 1);
    MFMA_QT(accA, 0);                // qt 0
    __syncthreads();                 // buf1 (qt1) ready; buf0 reads done

    STAGE(0, 2);
    MFMA_QT(accB, 1);                // qt 1
    ARGMAX_QT(accA, 0);
    __syncthreads();                 // buf0 (qt2) ready; buf1 reads done

    for (int i = 1; i <= 14; ++i) {
        const int qtA = 2 * i;       // even -> buf0
        STAGE(1, qtA + 1);
        MFMA_QT(accA, 0);            // qt 2i
        ARGMAX_QT(accB, qtA - 1);    // overlaps accA's pipe time
        __syncthreads();

        STAGE(0, qtA + 2);
        MFMA_QT(accB, 1);            // qt 2i+1
        ARGMAX_QT(accA, qtA);
        __syncthreads();
    }
    // staged so far: buf0 = qt30, processed through qt29 (argmax through 28... accB@29 pending)

    STAGE(1, 31);
    MFMA_QT(accA, 0);                // qt 30
    ARGMAX_QT(accB, 29);
    __syncthreads();                 // buf1 (qt31) ready

    MFMA_QT(accB, 1);                // qt 31
    ARGMAX_QT(accA, 30);
    ARGMAX_QT(accB, 31);

    // final: pack (acc = s+64 > 0 -> float bits monotone as uint),
    // shuffle-reduce over r15 (stays in q4 group), 1 atomic/row/wave
    #pragma unroll
    for (int mi = 0; mi < 2; ++mi)
        #pragma unroll
        for (int r = 0; r < 4; ++r) {
            u64 pk = ((u64)__float_as_uint(bestv[mi][r]) << 32)
                   | (u64)(0xFFFFFFFFu - bestq[mi][r]);
            #pragma unroll
            for (int d = 1; d < 16; d <<= 1) {
                u64 o = __shfl_xor((unsigned long long)pk, d);
                pk = o > pk ? o : pk;
            }
            if (r15 == 0)
                atomicMax(&packed[p0 + wm * 32 + mi * 16 + q4 * 4 + r], pk);
        }
}

// ---------------------------------------------------------------------------
// L: loss from the argmax's own similarity value (no gather).
// Decode: hi = bits(s+64) -> s = asfloat(hi) - 64; lo = ~q.
__global__ void loss_kernel(const u64* __restrict__ packed,
                            const float* __restrict__ sumsq_a, const float* __restrict__ sumsq_b,
                            float* __restrict__ out) {
    int p = blockIdx.x * 256 + threadIdx.x;
    u64 pk = packed[p];
    float s = __uint_as_float((u32)(pk >> 32)) - 64.0f;
    u32 q = 0xFFFFFFFFu - (u32)(pk & 0xFFFFFFFFull);
    float A = sumsq_a[p], B = sumsq_b[q];
    float dot = s * (sqrtf(B + EPS) + EPS);
    float cossim = dot / ((sqrtf(A) + EPS) * (sqrtf(B) + EPS));
    float v = (1.0f - cossim) * (1.0f / (float)HW);
    #pragma unroll
    for (int d = 1; d < 64; d <<= 1) v += __shfl_xor(v, d);
    if ((threadIdx.x & 63) == 0) atomicAdd(out, v);
}

// ---------------------------------------------------------------------------
extern "C" void kernel_launch(void* const* d_in, const int* in_sizes, int n_in,
                              void* d_out, int out_size, void* d_ws, size_t ws_size,
                              hipStream_t stream) {
    const float* a = (const float*)d_in[0];
    const float* b = (const float*)d_in[1];
    float* out = (float*)d_out;
    char* ws = (char*)d_ws;

    u8*    aF      = (u8*)ws;                                    // 4 MB
    u8*    bF      = (u8*)(ws + (size_t)4 * 1024 * 1024);        // 4 MB
    float* sumsq_a = (float*)(ws + (size_t)8 * 1024 * 1024);     // 64 KB
    float* sumsq_b = sumsq_a + HW;
    u64*   packed  = (u64*)(sumsq_b + HW);                       // 128 KB

    prep_kernel<<<dim3(HW / 32), 512, 0, stream>>>(a, b, sumsq_a, sumsq_b, aF, bF, packed, out);
    gemm_argmax<<<dim3((HW / BM) * (HW / NG)), 512, 0, stream>>>(aF, bF, packed);
    loss_kernel<<<dim3(HW / 256), 256, 0, stream>>>(packed, sumsq_a, sumsq_b, out);
}